// Round 14
// baseline (618.489 us; speedup 1.0000x reference)
//
#include <hip/hip_runtime.h>
#include <hip/hip_cooperative_groups.h>

namespace cg = cooperative_groups;

#define D_IN  256
#define D_HID 512
#define NEG_SLOPE 0.2f
#define SCAN_CHUNK 2048
#define COOP_GRID 512

typedef __attribute__((ext_vector_type(8))) short short8;
typedef __attribute__((ext_vector_type(4))) float floatx4;

__device__ __forceinline__ unsigned short f2bf(float f) {
    unsigned int u = __float_as_uint(f);
    u += 0x7fffu + ((u >> 16) & 1u);   // round-to-nearest-even
    return (unsigned short)(u >> 16);
}
__device__ __forceinline__ float bf2f(unsigned short u) {
    return __uint_as_float(((unsigned int)u) << 16);
}

__device__ __forceinline__ int eidx(const void* ei, long pos, int is64) {
    return is64 ? (int)((const long long*)ei)[pos] : ((const int*)ei)[pos];
}

// ---- init: x->bf16, weight transposes, outacc init (graph-independent work) ----
__global__ __launch_bounds__(256) void k_init(const float* __restrict__ x,
                                              unsigned short* __restrict__ xb,
                                              const float* __restrict__ W_gcn,
                                              unsigned short* __restrict__ Wgt,
                                              const float* __restrict__ W2,
                                              unsigned short* __restrict__ W2t,
                                              const float* __restrict__ b_out,
                                              float* __restrict__ outacc,
                                              int N, long xthreads) {
    long t = (long)blockIdx.x * blockDim.x + threadIdx.x;
    if (t < xthreads) {
        long i = t * 4;
        float4 v = *(const float4*)(x + i);
        ushort4 o;
        o.x = f2bf(v.x); o.y = f2bf(v.y); o.z = f2bf(v.z); o.w = f2bf(v.w);
        *(ushort4*)(xb + i) = o;
        return;
    }
    long u = t - xthreads;
    if (u < (long)D_IN * D_HID) {                 // Wgt [512,256]
        int tt = (int)u;
        int n = tt / D_IN, k = tt - n * D_IN;
        Wgt[tt] = f2bf(W_gcn[(long)k * D_HID + n]);
        return;
    }
    u -= (long)D_IN * D_HID;
    if (u < (long)D_HID * D_HID) {                // W2t [512,512]
        int tt = (int)u;
        int n = tt / D_HID, k = tt - n * D_HID;
        W2t[tt] = f2bf(W2[(long)k * D_HID + n]);
        return;
    }
    u -= (long)D_HID * D_HID;
    if (u < N) outacc[u] = b_out[0];
}

// ---- cooperative graph preprocessing: deg zero+count -> scan -> CSR fill ----
// one kernel, 5 grid syncs, replaces 4 separate dispatches
__global__ __launch_bounds__(256, 2) void k_graph(const void* __restrict__ ei,
                                                  int E, int N,
                                                  int* __restrict__ deg,
                                                  int* __restrict__ bsum,
                                                  int* __restrict__ bbase,
                                                  int* __restrict__ offs,
                                                  int* __restrict__ cursor,
                                                  float* __restrict__ dinv,
                                                  int* __restrict__ esrc) {
    cg::grid_group grid = cg::this_grid();
    const int tid = threadIdx.x, bid = blockIdx.x;
    const long gtid = (long)bid * 256 + tid;
    const long gsz  = (long)gridDim.x * 256;
    const int NBc = (N + SCAN_CHUNK - 1) / SCAN_CHUNK;

    // per-block dtype detect: odd 32-bit words of first 64 pairs all zero => int64
    int is64;
    {
        const unsigned int* w = (const unsigned int*)ei;
        unsigned int v = w[2 * (tid & 63) + 1];
        unsigned long long m = __ballot(v != 0);
        is64 = (m == 0ull) ? 1 : 0;
    }

    // A: zero degrees
    for (long i = gtid; i < N; i += gsz) deg[i] = 0;
    grid.sync();

    // B: count in-degrees
    for (long e = gtid; e < E; e += gsz)
        atomicAdd(&deg[eidx(ei, (long)E + e, is64)], 1);
    grid.sync();

    // C1: per-chunk sums
    if (bid < NBc) {
        int base = bid * SCAN_CHUNK;
        int hi = min(base + SCAN_CHUNK, N);
        int s = 0;
        for (int i = base + tid; i < hi; i += 256) s += deg[i];
#pragma unroll
        for (int o = 32; o > 0; o >>= 1) s += __shfl_down(s, o, 64);
        __shared__ int l4[4];
        if ((tid & 63) == 0) l4[tid >> 6] = s;
        __syncthreads();
        if (tid == 0) bsum[bid] = l4[0] + l4[1] + l4[2] + l4[3];
    }
    grid.sync();

    // C2: serial scan of NBc chunk sums (NBc ~ 25)
    if (bid == 0 && tid == 0) {
        int run = 0;
        for (int i = 0; i < NBc; ++i) { bbase[i] = run; run += bsum[i]; }
        offs[N] = run;
    }
    grid.sync();

    // C3: local scan per chunk -> offs/cursor/dinv
    if (bid < NBc) {
        __shared__ int lds[256];
        int base = bid * SCAN_CHUNK;
        int lo = base + tid * 8;
        int v[8], s = 0;
#pragma unroll
        for (int j = 0; j < 8; ++j) {
            int i = lo + j;
            v[j] = (i < N) ? deg[i] : 0;
            s += v[j];
        }
        lds[tid] = s;
        __syncthreads();
        for (int d = 1; d < 256; d <<= 1) {
            int add = (tid >= d) ? lds[tid - d] : 0;
            __syncthreads();
            lds[tid] += add;
            __syncthreads();
        }
        int run = bbase[bid] + ((tid > 0) ? lds[tid - 1] : 0);
#pragma unroll
        for (int j = 0; j < 8; ++j) {
            int i = lo + j;
            if (i < N) {
                offs[i] = run; cursor[i] = run;
                dinv[i] = rsqrtf(1.0f + (float)v[j]);
                run += v[j];
            }
        }
    }
    grid.sync();

    // D: fill CSR (src per slot, dst-sorted)
    for (long e = gtid; e < E; e += gsz) {
        int s = eidx(ei, e, is64), d = eidx(ei, (long)E + e, is64);
        int pos = atomicAdd(&cursor[d], 1);
        esrc[pos] = s;
    }
}

// ---- gather: wave=node, ushort8 loads (16 B/lane), 2 edges/load, 8-edge unroll ----
__global__ __launch_bounds__(256) void k_gather(const unsigned short* __restrict__ xb,
                                                const int* __restrict__ offs,
                                                const int* __restrict__ esrc,
                                                const float* __restrict__ dinv,
                                                unsigned short* __restrict__ aggb, int N) {
    int node = blockIdx.x * 4 + (threadIdx.x >> 6);
    int lane = threadIdx.x & 63;
    if (node >= N) return;
    int half = lane >> 5;          // which edge of a pair this lane handles
    int li   = lane & 31;          // 32 lanes x ushort8 = 256 cols
    int colofs = li * 8;
    float di = dinv[node];

    float a[8];
    {
        short8 v = *(const short8*)(xb + (long)node * D_IN + colofs);
#pragma unroll
        for (int j = 0; j < 8; ++j)
            a[j] = (half == 0) ? di * bf2f((unsigned short)v[j]) : 0.f;
    }

    int beg = offs[node], end = offs[node + 1];
    int e = beg;
    for (; e + 8 <= end; e += 8) {      // 4 x 1KB wave-loads in flight
        int s0 = esrc[e + half];
        int s1 = esrc[e + 2 + half];
        int s2 = esrc[e + 4 + half];
        int s3 = esrc[e + 6 + half];
        float w0 = dinv[s0], w1 = dinv[s1], w2 = dinv[s2], w3 = dinv[s3];
        short8 u0 = *(const short8*)(xb + (long)s0 * D_IN + colofs);
        short8 u1 = *(const short8*)(xb + (long)s1 * D_IN + colofs);
        short8 u2 = *(const short8*)(xb + (long)s2 * D_IN + colofs);
        short8 u3 = *(const short8*)(xb + (long)s3 * D_IN + colofs);
#pragma unroll
        for (int j = 0; j < 8; ++j)
            a[j] += w0 * bf2f((unsigned short)u0[j]) + w1 * bf2f((unsigned short)u1[j])
                  + w2 * bf2f((unsigned short)u2[j]) + w3 * bf2f((unsigned short)u3[j]);
    }
    for (; e < end; e += 2) {           // guarded 2-edge tail
        int j0 = e + half;
        int jj = (j0 < end) ? j0 : end - 1;
        int s = esrc[jj];
        float w = (j0 < end) ? dinv[s] : 0.f;
        short8 u = *(const short8*)(xb + (long)s * D_IN + colofs);
#pragma unroll
        for (int j = 0; j < 8; ++j)
            a[j] += w * bf2f((unsigned short)u[j]);
    }

#pragma unroll
    for (int j = 0; j < 8; ++j) a[j] += __shfl_xor(a[j], 32, 64);

    if (half == 0) {
        short8 o;
#pragma unroll
        for (int j = 0; j < 8; ++j) o[j] = (short)f2bf(a[j] * di);
        *(short8*)(aggb + (long)node * D_IN + colofs) = o;
    }
}

// ============ swizzled-LDS 128x128 GEMM machinery ============
__device__ __forceinline__ void async_cp16(const unsigned short* gp, unsigned short* lp) {
    __builtin_amdgcn_global_load_lds((const __attribute__((address_space(1))) void*)gp,
                                     (__attribute__((address_space(3))) void*)lp, 16, 0, 0);
}

__device__ __forceinline__ void stage_sw(const unsigned short* src, int strideK,
                                         int rowMax, unsigned short* lds, int tid) {
#pragma unroll
    for (int rr = 0; rr < 2; ++rr) {
        int c = rr * 256 + tid;
        int p = c >> 3;
        int ci = (c & 7) ^ (p & 7);
        int row = 2 * p + (ci >> 2);
        if (row > rowMax) row = rowMax;
        async_cp16(src + (long)row * strideK + (ci & 3) * 8, lds + c * 8);
    }
}

__device__ __forceinline__ bool map_block(int b, int M, int& m0, int& n0) {
    int x = b & 7, slot = b >> 3;
    int mt = x + 8 * (slot >> 2);
    m0 = mt * 128; n0 = (slot & 3) * 128;
    return m0 < M;
}

// ---- GEMM1: C[M,512] = bf16(leaky(A[M,K] @ Bt[512,K]^T + bias)), LDS-staged store ----
__global__ __launch_bounds__(256) void k_gemm_bf16(const unsigned short* __restrict__ A,
                                                   const unsigned short* __restrict__ Bt,
                                                   const float* __restrict__ bias,
                                                   unsigned short* __restrict__ C,
                                                   int M, int K) {
    __shared__ __align__(16) unsigned short As[128 * 32];
    __shared__ __align__(16) unsigned short Bs[128 * 32];
    __shared__ __align__(16) unsigned short Ep[32 * 128];   // epilogue staging, 8 KB
    const int tid  = threadIdx.x;
    const int lane = tid & 63, wave = tid >> 6;
    int m0, n0;
    if (!map_block(blockIdx.x, M, m0, n0)) return;
    const int r = lane & 15, q = lane >> 4;
    const int rh = r >> 1;
    const int sa = (((r & 1) << 2) | q) ^ rh;
    const int wm = (wave & 1) * 64, wn = (wave >> 1) * 64;
    const int band = wm >> 6;      // 0 or 1

    floatx4 acc[4][4];
#pragma unroll
    for (int i = 0; i < 4; ++i)
#pragma unroll
        for (int j = 0; j < 4; ++j) acc[i][j] = (floatx4){0.f, 0.f, 0.f, 0.f};

    for (int k0 = 0; k0 < K; k0 += 32) {
        stage_sw(A + (long)m0 * K + k0, K, M - 1 - m0, As, tid);
        stage_sw(Bt + (long)n0 * K + k0, K, 127, Bs, tid);
        __syncthreads();

        short8 af[4], bf[4];
#pragma unroll
        for (int i = 0; i < 4; ++i)
            af[i] = *(const short8*)(As + (wm / 2 + i * 8 + rh) * 64 + sa * 8);
#pragma unroll
        for (int j = 0; j < 4; ++j)
            bf[j] = *(const short8*)(Bs + (wn / 2 + j * 8 + rh) * 64 + sa * 8);
#pragma unroll
        for (int i = 0; i < 4; ++i)
#pragma unroll
            for (int j = 0; j < 4; ++j)
                acc[i][j] = __builtin_amdgcn_mfma_f32_16x16x32_bf16(af[i], bf[j], acc[i][j], 0, 0, 0);
        __syncthreads();
    }

    // epilogue: per i-band, stage 32 rows x 128 cols bf16 in LDS, then 16B/lane stores
    float bv[4];
#pragma unroll
    for (int j = 0; j < 4; ++j) bv[j] = bias[n0 + wn + j * 16 + r];

#pragma unroll
    for (int i = 0; i < 4; ++i) {
#pragma unroll
        for (int j = 0; j < 4; ++j) {
#pragma unroll
            for (int t2 = 0; t2 < 4; ++t2) {
                float v = acc[i][j][t2] + bv[j];
                v = v > 0.f ? v : NEG_SLOPE * v;
                Ep[(band * 16 + q * 4 + t2) * 128 + wn + j * 16 + r] = f2bf(v);
            }
        }
        __syncthreads();
#pragma unroll
        for (int rr = 0; rr < 2; ++rr) {
            int c = rr * 256 + tid;        // 512 chunks of 16B
            int lrow = c >> 4, ccol = c & 15;
            int grow = m0 + (lrow >> 4) * 64 + i * 16 + (lrow & 15);
            if (grow < M) {
                short8 v = *(const short8*)(Ep + lrow * 128 + ccol * 8);
                *(short8*)(C + (long)grow * D_HID + n0 + ccol * 8) = v;
            }
        }
        __syncthreads();
    }
}

// ---- GEMM2 fused with head: outacc[row] += sum_col leaky(A@Bt^T + b2) * wout[col] ----
__global__ __launch_bounds__(256) void k_gemm2f(const unsigned short* __restrict__ A,
                                                const unsigned short* __restrict__ Bt,
                                                const float* __restrict__ bias,
                                                const float* __restrict__ wout,
                                                float* __restrict__ outacc,
                                                int M, int K) {
    __shared__ __align__(16) unsigned short As[128 * 32];
    __shared__ __align__(16) unsigned short Bs[128 * 32];
    const int tid  = threadIdx.x;
    const int lane = tid & 63, wave = tid >> 6;
    int m0, n0;
    if (!map_block(blockIdx.x, M, m0, n0)) return;
    const int r = lane & 15, q = lane >> 4;
    const int rh = r >> 1;
    const int sa = (((r & 1) << 2) | q) ^ rh;
    const int wm = (wave & 1) * 64, wn = (wave >> 1) * 64;

    floatx4 acc[4][4];
#pragma unroll
    for (int i = 0; i < 4; ++i)
#pragma unroll
        for (int j = 0; j < 4; ++j) acc[i][j] = (floatx4){0.f, 0.f, 0.f, 0.f};

    for (int k0 = 0; k0 < K; k0 += 32) {
        stage_sw(A + (long)m0 * K + k0, K, M - 1 - m0, As, tid);
        stage_sw(Bt + (long)n0 * K + k0, K, 127, Bs, tid);
        __syncthreads();

        short8 af[4], bf[4];
#pragma unroll
        for (int i = 0; i < 4; ++i)
            af[i] = *(const short8*)(As + (wm / 2 + i * 8 + rh) * 64 + sa * 8);
#pragma unroll
        for (int j = 0; j < 4; ++j)
            bf[j] = *(const short8*)(Bs + (wn / 2 + j * 8 + rh) * 64 + sa * 8);
#pragma unroll
        for (int i = 0; i < 4; ++i)
#pragma unroll
            for (int j = 0; j < 4; ++j)
                acc[i][j] = __builtin_amdgcn_mfma_f32_16x16x32_bf16(af[i], bf[j], acc[i][j], 0, 0, 0);
        __syncthreads();
    }

    float bv[4], wv[4];
#pragma unroll
    for (int j = 0; j < 4; ++j) {
        int col = n0 + wn + j * 16 + r;
        bv[j] = bias[col];
        wv[j] = wout[col];
    }
#pragma unroll
    for (int i = 0; i < 4; ++i) {
#pragma unroll
        for (int t2 = 0; t2 < 4; ++t2) {
            float p = 0.f;
#pragma unroll
            for (int j = 0; j < 4; ++j) {
                float v = acc[i][j][t2] + bv[j];
                v = v > 0.f ? v : NEG_SLOPE * v;
                p += v * wv[j];
            }
            p += __shfl_xor(p, 8, 64);
            p += __shfl_xor(p, 4, 64);
            p += __shfl_xor(p, 2, 64);
            p += __shfl_xor(p, 1, 64);
            if (r == 0) {
                int row = m0 + wm + i * 16 + q * 4 + t2;
                if (row < M) atomicAdd(&outacc[row], p);
            }
        }
    }
}

// ---- final: plain-store copy outacc (ws) -> d_out ----
__global__ void k_out(const float* __restrict__ outacc, float* __restrict__ out, int N) {
    int i = blockIdx.x * blockDim.x + threadIdx.x;
    if (i < N) out[i] = outacc[i];
}

extern "C" void kernel_launch(void* const* d_in, const int* in_sizes, int n_in,
                              void* d_out, int out_size, void* d_ws, size_t ws_size,
                              hipStream_t stream) {
    const float* x     = (const float*)d_in[0];
    const void*  ei    = d_in[1];
    const float* W_gcn = (const float*)d_in[2];
    const float* b_gcn = (const float*)d_in[3];
    const float* W2    = (const float*)d_in[4];
    const float* b2    = (const float*)d_in[5];
    const float* W_out = (const float*)d_in[6];
    const float* b_out = (const float*)d_in[7];
    float* out = (float*)d_out;

    int N = in_sizes[0] / D_IN;
    int E = in_sizes[1] / 2;
    const int NB = (N + SCAN_CHUNK - 1) / SCAN_CHUNK;

    char* w = (char*)d_ws;
    size_t off = 0;
    auto alloc = [&](size_t bytes) { char* p = w + off; off = (off + bytes + 255) & ~(size_t)255; return p; };
    float*          dinv   = (float*)alloc((size_t)N * 4);
    int*            deg_i  = (int*)alloc((size_t)N * 4);
    int*            offs   = (int*)alloc((size_t)(N + 1) * 4);
    int*            cursor = (int*)alloc((size_t)N * 4);
    float*          outacc = (float*)alloc((size_t)N * 4);
    int*            bsum   = (int*)alloc((size_t)NB * 4);
    int*            bbase  = (int*)alloc((size_t)NB * 4);
    int*            esrc   = (int*)alloc((size_t)(E + 16) * 4);
    unsigned short* xb     = (unsigned short*)alloc((size_t)N * D_IN * 2);
    unsigned short* aggb   = (unsigned short*)alloc((size_t)N * D_IN * 2);
    unsigned short* h1     = (unsigned short*)alloc((size_t)N * D_HID * 2);
    unsigned short* Wgt    = (unsigned short*)alloc((size_t)D_IN * D_HID * 2);
    unsigned short* W2t    = (unsigned short*)alloc((size_t)D_HID * D_HID * 2);

    long xthreads = ((long)N * D_IN) / 4;
    long prep_elems = (long)D_IN * D_HID + (long)D_HID * D_HID + N;
    long tot_threads = xthreads + prep_elems;
    k_init<<<(unsigned)((tot_threads + 255) / 256), 256, 0, stream>>>(
        x, xb, W_gcn, Wgt, W2, W2t, b_out, outacc, N, xthreads);

    void* kargs[] = { (void*)&ei, (void*)&E, (void*)&N, (void*)&deg_i, (void*)&bsum,
                      (void*)&bbase, (void*)&offs, (void*)&cursor, (void*)&dinv, (void*)&esrc };
    hipLaunchCooperativeKernel((const void*)k_graph, dim3(COOP_GRID), dim3(256),
                               kargs, 0, stream);

    k_gather<<<(N + 3) / 4, 256, 0, stream>>>(xb, offs, esrc, dinv, aggb, N);

    int mtiles = (N + 127) / 128;
    int gblocks = ((mtiles + 7) / 8) * 8 * 4;
    k_gemm_bf16<<<gblocks, 256, 0, stream>>>(aggb, Wgt, b_gcn, h1, N, D_IN);
    k_gemm2f<<<gblocks, 256, 0, stream>>>(h1, W2t, b2, W_out, outacc, N, D_HID);

    k_out<<<(N + 255) / 256, 256, 0, stream>>>(outacc, out, N);
}

// Round 16
// 324.630 us; speedup vs baseline: 1.9052x; 1.9052x over previous
//
#include <hip/hip_runtime.h>

#define D_IN  256
#define D_HID 512
#define NEG_SLOPE 0.2f
#define SCAN_CHUNK 2048

typedef __attribute__((ext_vector_type(8))) short short8;
typedef __attribute__((ext_vector_type(4))) float floatx4;

__device__ __forceinline__ unsigned short f2bf(float f) {
    unsigned int u = __float_as_uint(f);
    u += 0x7fffu + ((u >> 16) & 1u);   // round-to-nearest-even
    return (unsigned short)(u >> 16);
}
__device__ __forceinline__ float bf2f(unsigned short u) {
    return __uint_as_float(((unsigned int)u) << 16);
}

__device__ __forceinline__ int eidx(const void* ei, long pos, int is64) {
    return is64 ? (int)((const long long*)ei)[pos] : ((const int*)ei)[pos];
}

// ---- init: x->bf16, zero deg, dtype detect (block 0), weight transposes, outacc init ----
// (r13 version — passed post-timing validation; do not touch)
__global__ __launch_bounds__(256) void k_init(const float* __restrict__ x,
                                              unsigned short* __restrict__ xb,
                                              int* __restrict__ deg, int N,
                                              const unsigned int* __restrict__ ei,
                                              int npairs, int* flag,
                                              const float* __restrict__ W_gcn,
                                              unsigned short* __restrict__ Wgt,
                                              const float* __restrict__ W2,
                                              unsigned short* __restrict__ W2t,
                                              const float* __restrict__ b_out,
                                              float* __restrict__ outacc,
                                              long xthreads) {
    long t = (long)blockIdx.x * blockDim.x + threadIdx.x;
    if (t < xthreads) {
        long i = t * 4;
        float4 v = *(const float4*)(x + i);
        ushort4 o;
        o.x = f2bf(v.x); o.y = f2bf(v.y); o.z = f2bf(v.z); o.w = f2bf(v.w);
        *(ushort4*)(xb + i) = o;
        if (t < N) deg[t] = 0;
        if (blockIdx.x == 0) {
            __shared__ int nz;
            if (threadIdx.x == 0) nz = 0;
            __syncthreads();
            for (int p = threadIdx.x; p < npairs; p += blockDim.x)
                if (ei[2 * p + 1] != 0) nz = 1;
            __syncthreads();
            if (threadIdx.x == 0) *flag = nz ? 0 : 1;   // 1 => int64
        }
        return;
    }
    long u = t - xthreads;
    if (u < (long)D_IN * D_HID) {                 // Wgt [512,256]
        int tt = (int)u;
        int n = tt / D_IN, k = tt - n * D_IN;
        Wgt[tt] = f2bf(W_gcn[(long)k * D_HID + n]);
        return;
    }
    u -= (long)D_IN * D_HID;
    if (u < (long)D_HID * D_HID) {                // W2t [512,512]
        int tt = (int)u;
        int n = tt / D_HID, k = tt - n * D_HID;
        W2t[tt] = f2bf(W2[(long)k * D_HID + n]);
        return;
    }
    u -= (long)D_HID * D_HID;
    if (u < N) outacc[u] = b_out[0];
}

// ---- degree count (int only) ----
__global__ void k_deg_count(const void* __restrict__ ei, const int* __restrict__ flag,
                            int* __restrict__ deg, int E) {
    int e = blockIdx.x * blockDim.x + threadIdx.x;
    if (e < E) atomicAdd(&deg[eidx(ei, (long)E + e, *flag)], 1);
}

// ---- scan phase 1: per-chunk sums ----
__global__ __launch_bounds__(256) void k_scan1(const int* __restrict__ deg,
                                               int* __restrict__ bsum, int N) {
    int base = blockIdx.x * SCAN_CHUNK;
    int hi = min(base + SCAN_CHUNK, N);
    int s = 0;
    for (int i = base + threadIdx.x; i < hi; i += 256) s += deg[i];
#pragma unroll
    for (int off = 32; off > 0; off >>= 1) s += __shfl_down(s, off, 64);
    __shared__ int lds[4];
    if ((threadIdx.x & 63) == 0) lds[threadIdx.x >> 6] = s;
    __syncthreads();
    if (threadIdx.x == 0) bsum[blockIdx.x] = lds[0] + lds[1] + lds[2] + lds[3];
}

// ---- scan phases 2+3 merged ----
__global__ __launch_bounds__(256) void k_scan23(const int* __restrict__ deg,
                                                const int* __restrict__ bsum, int NB,
                                                int* __restrict__ offs,
                                                int* __restrict__ cursor,
                                                float* __restrict__ dinv, int N) {
    __shared__ int lds[256];
    int t = threadIdx.x;
    int bbase = 0;
    for (int i = 0; i < NB; ++i) bbase += (i < blockIdx.x) ? bsum[i] : 0;
    if (blockIdx.x == NB - 1 && t == 0) offs[N] = bbase + bsum[NB - 1];
    int base = blockIdx.x * SCAN_CHUNK;
    int lo = base + t * 8;
    int v[8], s = 0;
#pragma unroll
    for (int j = 0; j < 8; ++j) {
        int i = lo + j;
        v[j] = (i < N) ? deg[i] : 0;
        s += v[j];
    }
    lds[t] = s;
    __syncthreads();
    for (int d = 1; d < 256; d <<= 1) {
        int add = (t >= d) ? lds[t - d] : 0;
        __syncthreads();
        lds[t] += add;
        __syncthreads();
    }
    int run = bbase + ((t > 0) ? lds[t - 1] : 0);
#pragma unroll
    for (int j = 0; j < 8; ++j) {
        int i = lo + j;
        if (i < N) {
            offs[i] = run; cursor[i] = run;
            dinv[i] = rsqrtf(1.0f + (float)v[j]);
            run += v[j];
        }
    }
}

// ---- fill CSR edge list (src per slot, dst-sorted) ----
__global__ void k_fill(const void* __restrict__ ei, const int* __restrict__ flag,
                       int* __restrict__ cursor, int* __restrict__ esrc, int E) {
    int e = blockIdx.x * blockDim.x + threadIdx.x;
    if (e >= E) return;
    int is64 = *flag;
    int s = eidx(ei, e, is64), d = eidx(ei, (long)E + e, is64);
    int pos = atomicAdd(&cursor[d], 1);
    esrc[pos] = s;
}

// ---- gather: wave=node, ushort8 loads (16 B/lane), 2 edges/load, 8-edge unroll ----
__global__ __launch_bounds__(256) void k_gather(const unsigned short* __restrict__ xb,
                                                const int* __restrict__ offs,
                                                const int* __restrict__ esrc,
                                                const float* __restrict__ dinv,
                                                unsigned short* __restrict__ aggb, int N) {
    int node = blockIdx.x * 4 + (threadIdx.x >> 6);
    int lane = threadIdx.x & 63;
    if (node >= N) return;
    int half = lane >> 5;
    int li   = lane & 31;
    int colofs = li * 8;
    float di = dinv[node];

    float a[8];
    {
        short8 v = *(const short8*)(xb + (long)node * D_IN + colofs);
#pragma unroll
        for (int j = 0; j < 8; ++j)
            a[j] = (half == 0) ? di * bf2f((unsigned short)v[j]) : 0.f;
    }

    int beg = offs[node], end = offs[node + 1];
    int e = beg;
    for (; e + 8 <= end; e += 8) {      // 4 x 1KB wave-loads in flight
        int s0 = esrc[e + half];
        int s1 = esrc[e + 2 + half];
        int s2 = esrc[e + 4 + half];
        int s3 = esrc[e + 6 + half];
        float w0 = dinv[s0], w1 = dinv[s1], w2 = dinv[s2], w3 = dinv[s3];
        short8 u0 = *(const short8*)(xb + (long)s0 * D_IN + colofs);
        short8 u1 = *(const short8*)(xb + (long)s1 * D_IN + colofs);
        short8 u2 = *(const short8*)(xb + (long)s2 * D_IN + colofs);
        short8 u3 = *(const short8*)(xb + (long)s3 * D_IN + colofs);
#pragma unroll
        for (int j = 0; j < 8; ++j)
            a[j] += w0 * bf2f((unsigned short)u0[j]) + w1 * bf2f((unsigned short)u1[j])
                  + w2 * bf2f((unsigned short)u2[j]) + w3 * bf2f((unsigned short)u3[j]);
    }
    for (; e < end; e += 2) {
        int j0 = e + half;
        int jj = (j0 < end) ? j0 : end - 1;
        int s = esrc[jj];
        float w = (j0 < end) ? dinv[s] : 0.f;
        short8 u = *(const short8*)(xb + (long)s * D_IN + colofs);
#pragma unroll
        for (int j = 0; j < 8; ++j)
            a[j] += w * bf2f((unsigned short)u[j]);
    }

#pragma unroll
    for (int j = 0; j < 8; ++j) a[j] += __shfl_xor(a[j], 32, 64);

    if (half == 0) {
        short8 o;
#pragma unroll
        for (int j = 0; j < 8; ++j) o[j] = (short)f2bf(a[j] * di);
        *(short8*)(aggb + (long)node * D_IN + colofs) = o;
    }
}

// ============ BK=64 swizzled-LDS 128x128 GEMM machinery ============
// LDS tile: 128 rows x 64 shorts (128 B/row); 16B chunk ci of row stored at
// slot ci ^ (row & 7)  -> fragment ds_read_b128 spreads 8 rows over 8 slots.
__device__ __forceinline__ void async_cp16(const unsigned short* gp, unsigned short* lp) {
    __builtin_amdgcn_global_load_lds((const __attribute__((address_space(1))) void*)gp,
                                     (__attribute__((address_space(3))) void*)lp, 16, 0, 0);
}

__device__ __forceinline__ void stage_sw64(const unsigned short* src, int strideK,
                                           int rowMax, unsigned short* lds, int tid) {
#pragma unroll
    for (int rr = 0; rr < 4; ++rr) {
        int c = rr * 256 + tid;          // 0..1023 16B chunks
        int row = c >> 3;
        int ci = (c & 7) ^ (row & 7);    // logical chunk stored at this slot
        if (row > rowMax) row = rowMax;
        async_cp16(src + (long)row * strideK + ci * 8, lds + c * 8);
    }
}

__device__ __forceinline__ bool map_block(int b, int M, int& m0, int& n0) {
    int x = b & 7, slot = b >> 3;
    int mt = x + 8 * (slot >> 2);
    m0 = mt * 128; n0 = (slot & 3) * 128;
    return m0 < M;
}

// ---- GEMM1: C[M,512] = bf16(leaky(A[M,K] @ Bt[512,K]^T + bias)), LDS-staged store ----
__global__ __launch_bounds__(256) void k_gemm_bf16(const unsigned short* __restrict__ A,
                                                   const unsigned short* __restrict__ Bt,
                                                   const float* __restrict__ bias,
                                                   unsigned short* __restrict__ C,
                                                   int M, int K) {
    __shared__ __align__(16) unsigned short As[128 * 64];   // 16 KB
    __shared__ __align__(16) unsigned short Bs[128 * 64];   // 16 KB
    __shared__ __align__(16) unsigned short Ep[32 * 128];   // epilogue staging, 8 KB
    const int tid  = threadIdx.x;
    const int lane = tid & 63, wave = tid >> 6;
    int m0, n0;
    if (!map_block(blockIdx.x, M, m0, n0)) return;
    const int r = lane & 15, q = lane >> 4;
    const int xv = r & 7;                      // XOR swizzle value for this lane's rows
    const int wm = (wave & 1) * 64, wn = (wave >> 1) * 64;
    const int band = wm >> 6;

    floatx4 acc[4][4];
#pragma unroll
    for (int i = 0; i < 4; ++i)
#pragma unroll
        for (int j = 0; j < 4; ++j) acc[i][j] = (floatx4){0.f, 0.f, 0.f, 0.f};

    for (int k0 = 0; k0 < K; k0 += 64) {
        stage_sw64(A + (long)m0 * K + k0, K, M - 1 - m0, As, tid);
        stage_sw64(Bt + (long)n0 * K + k0, K, 127, Bs, tid);
        __syncthreads();

#pragma unroll
        for (int s = 0; s < 2; ++s) {          // two K=32 sub-steps per tile
            int slotbase = s * 4 + q;
            short8 af[4], bf[4];
#pragma unroll
            for (int i = 0; i < 4; ++i)
                af[i] = *(const short8*)(As + (wm + i * 16 + r) * 64 + (slotbase ^ xv) * 8);
#pragma unroll
            for (int j = 0; j < 4; ++j)
                bf[j] = *(const short8*)(Bs + (wn + j * 16 + r) * 64 + (slotbase ^ xv) * 8);
#pragma unroll
            for (int i = 0; i < 4; ++i)
#pragma unroll
                for (int j = 0; j < 4; ++j)
                    acc[i][j] = __builtin_amdgcn_mfma_f32_16x16x32_bf16(af[i], bf[j], acc[i][j], 0, 0, 0);
        }
        __syncthreads();
    }

    // epilogue: per i-band, stage 32 rows x 128 cols bf16 in LDS, then 16B/lane stores
    float bv[4];
#pragma unroll
    for (int j = 0; j < 4; ++j) bv[j] = bias[n0 + wn + j * 16 + r];

#pragma unroll
    for (int i = 0; i < 4; ++i) {
#pragma unroll
        for (int j = 0; j < 4; ++j) {
#pragma unroll
            for (int t2 = 0; t2 < 4; ++t2) {
                float v = acc[i][j][t2] + bv[j];
                v = v > 0.f ? v : NEG_SLOPE * v;
                Ep[(band * 16 + q * 4 + t2) * 128 + wn + j * 16 + r] = f2bf(v);
            }
        }
        __syncthreads();
#pragma unroll
        for (int rr = 0; rr < 2; ++rr) {
            int c = rr * 256 + tid;
            int lrow = c >> 4, ccol = c & 15;
            int grow = m0 + (lrow >> 4) * 64 + i * 16 + (lrow & 15);
            if (grow < M) {
                short8 v = *(const short8*)(Ep + lrow * 128 + ccol * 8);
                *(short8*)(C + (long)grow * D_HID + n0 + ccol * 8) = v;
            }
        }
        __syncthreads();
    }
}

// ---- GEMM2 fused with head: outacc[row] += sum_col leaky(A@Bt^T + b2) * wout[col] ----
__global__ __launch_bounds__(256) void k_gemm2f(const unsigned short* __restrict__ A,
                                                const unsigned short* __restrict__ Bt,
                                                const float* __restrict__ bias,
                                                const float* __restrict__ wout,
                                                float* __restrict__ outacc,
                                                int M, int K) {
    __shared__ __align__(16) unsigned short As[128 * 64];
    __shared__ __align__(16) unsigned short Bs[128 * 64];
    const int tid  = threadIdx.x;
    const int lane = tid & 63, wave = tid >> 6;
    int m0, n0;
    if (!map_block(blockIdx.x, M, m0, n0)) return;
    const int r = lane & 15, q = lane >> 4;
    const int xv = r & 7;
    const int wm = (wave & 1) * 64, wn = (wave >> 1) * 64;

    floatx4 acc[4][4];
#pragma unroll
    for (int i = 0; i < 4; ++i)
#pragma unroll
        for (int j = 0; j < 4; ++j) acc[i][j] = (floatx4){0.f, 0.f, 0.f, 0.f};

    for (int k0 = 0; k0 < K; k0 += 64) {
        stage_sw64(A + (long)m0 * K + k0, K, M - 1 - m0, As, tid);
        stage_sw64(Bt + (long)n0 * K + k0, K, 127, Bs, tid);
        __syncthreads();

#pragma unroll
        for (int s = 0; s < 2; ++s) {
            int slotbase = s * 4 + q;
            short8 af[4], bf[4];
#pragma unroll
            for (int i = 0; i < 4; ++i)
                af[i] = *(const short8*)(As + (wm + i * 16 + r) * 64 + (slotbase ^ xv) * 8);
#pragma unroll
            for (int j = 0; j < 4; ++j)
                bf[j] = *(const short8*)(Bs + (wn + j * 16 + r) * 64 + (slotbase ^ xv) * 8);
#pragma unroll
            for (int i = 0; i < 4; ++i)
#pragma unroll
                for (int j = 0; j < 4; ++j)
                    acc[i][j] = __builtin_amdgcn_mfma_f32_16x16x32_bf16(af[i], bf[j], acc[i][j], 0, 0, 0);
        }
        __syncthreads();
    }

    float bv[4], wv[4];
#pragma unroll
    for (int j = 0; j < 4; ++j) {
        int col = n0 + wn + j * 16 + r;
        bv[j] = bias[col];
        wv[j] = wout[col];
    }
#pragma unroll
    for (int i = 0; i < 4; ++i) {
#pragma unroll
        for (int t2 = 0; t2 < 4; ++t2) {
            float p = 0.f;
#pragma unroll
            for (int j = 0; j < 4; ++j) {
                float v = acc[i][j][t2] + bv[j];
                v = v > 0.f ? v : NEG_SLOPE * v;
                p += v * wv[j];
            }
            p += __shfl_xor(p, 8, 64);
            p += __shfl_xor(p, 4, 64);
            p += __shfl_xor(p, 2, 64);
            p += __shfl_xor(p, 1, 64);
            if (r == 0) {
                int row = m0 + wm + i * 16 + q * 4 + t2;
                if (row < M) atomicAdd(&outacc[row], p);
            }
        }
    }
}

// ---- final: plain-store copy outacc (ws) -> d_out ----
__global__ void k_out(const float* __restrict__ outacc, float* __restrict__ out, int N) {
    int i = blockIdx.x * blockDim.x + threadIdx.x;
    if (i < N) out[i] = outacc[i];
}

extern "C" void kernel_launch(void* const* d_in, const int* in_sizes, int n_in,
                              void* d_out, int out_size, void* d_ws, size_t ws_size,
                              hipStream_t stream) {
    const float* x     = (const float*)d_in[0];
    const void*  ei    = d_in[1];
    const float* W_gcn = (const float*)d_in[2];
    const float* b_gcn = (const float*)d_in[3];
    const float* W2    = (const float*)d_in[4];
    const float* b2    = (const float*)d_in[5];
    const float* W_out = (const float*)d_in[6];
    const float* b_out = (const float*)d_in[7];
    float* out = (float*)d_out;

    const int N = in_sizes[0] / D_IN;
    const int E = in_sizes[1] / 2;
    const int NB = (N + SCAN_CHUNK - 1) / SCAN_CHUNK;

    char* w = (char*)d_ws;
    size_t off = 0;
    auto alloc = [&](size_t bytes) { char* p = w + off; off = (off + bytes + 255) & ~(size_t)255; return p; };
    int*            flag   = (int*)alloc(256);
    float*          dinv   = (float*)alloc((size_t)N * 4);
    int*            deg_i  = (int*)alloc((size_t)N * 4);
    int*            offs   = (int*)alloc((size_t)(N + 1) * 4);
    int*            cursor = (int*)alloc((size_t)N * 4);
    float*          outacc = (float*)alloc((size_t)N * 4);
    int*            bsum   = (int*)alloc((size_t)NB * 4);
    int*            esrc   = (int*)alloc((size_t)(E + 16) * 4);
    unsigned short* xb     = (unsigned short*)alloc((size_t)N * D_IN * 2);
    unsigned short* aggb   = (unsigned short*)alloc((size_t)N * D_IN * 2);
    unsigned short* h1     = (unsigned short*)alloc((size_t)N * D_HID * 2);
    unsigned short* Wgt    = (unsigned short*)alloc((size_t)D_IN * D_HID * 2);
    unsigned short* W2t    = (unsigned short*)alloc((size_t)D_HID * D_HID * 2);

    int npairs = E < 2048 ? E : 2048;
    long xthreads = ((long)N * D_IN) / 4;
    long prep_elems = (long)D_IN * D_HID + (long)D_HID * D_HID + N;
    long tot_threads = xthreads + prep_elems;
    k_init<<<(unsigned)((tot_threads + 255) / 256), 256, 0, stream>>>(
        x, xb, deg_i, N, (const unsigned int*)ei, npairs, flag,
        W_gcn, Wgt, W2, W2t, b_out, outacc, xthreads);

    k_deg_count<<<(E + 255) / 256, 256, 0, stream>>>(ei, flag, deg_i, E);
    k_scan1<<<NB, 256, 0, stream>>>(deg_i, bsum, N);
    k_scan23<<<NB, 256, 0, stream>>>(deg_i, bsum, NB, offs, cursor, dinv, N);
    k_fill<<<(E + 255) / 256, 256, 0, stream>>>(ei, flag, cursor, esrc, E);

    k_gather<<<(N + 3) / 4, 256, 0, stream>>>(xb, offs, esrc, dinv, aggb, N);

    int mtiles = (N + 127) / 128;
    int gblocks = ((mtiles + 7) / 8) * 8 * 4;
    k_gemm_bf16<<<gblocks, 256, 0, stream>>>(aggb, Wgt, b_gcn, h1, N, D_IN);
    k_gemm2f<<<gblocks, 256, 0, stream>>>(h1, W2t, b2, W_out, outacc, N, D_HID);

    k_out<<<(N + 255) / 256, 256, 0, stream>>>(outacc, out, N);
}